// Round 1
// baseline (628.033 us; speedup 1.0000x reference)
//
#include <hip/hip_runtime.h>
#include <stdint.h>

// ---------------------------------------------------------------------------
// BitAttention: x@sign(wq)^T*sq -> GQA causal flash attn -> @sign(wo)^T*so
// Round 1: correctness-first bf16 MFMA pipeline.
//   - scales: deterministic 2-pass |w| mean (no float atomics)
//   - gemm_bt: m97-style 128x128xBK64 tile, global_load_lds(16B), 2-barrier
//   - flash_attn: 4 waves x 16 q-rows, KVBLK=64, V reg-transposed into LDS
// ws layout (bytes):
//   [0,2048)    double partials[256]
//   [2048,2064) float scales[4] (q,k,v,o)
//   [4096, ...) xb(16M) wqs(8M) wks(2M) wvs(2M) wos(8M) qb(16M) kb(4M) vb(4M) ao(16M)
// ---------------------------------------------------------------------------

#define D_MODEL 2048
#define S_LEN   2048
#define BATCH   2
#define NKV     8
#define HD      64
#define MROWS   (BATCH * S_LEN)   // 4096
#define KV_DIM  (NKV * HD)        // 512

typedef unsigned short u16;
typedef __bf16 bf16x8 __attribute__((ext_vector_type(8)));
typedef float  f32x4  __attribute__((ext_vector_type(4)));

__device__ __forceinline__ u16 f2bf(float f) {
  union { float f; unsigned u; } v; v.f = f;
  unsigned r = v.u + 0x7FFFu + ((v.u >> 16) & 1u);   // RNE
  return (u16)(r >> 16);
}

__device__ __forceinline__ void lds_load16(u16* lds, const u16* g) {
  // dest = wave-uniform LDS base + lane*16 (HW rule); src is per-lane.
  __builtin_amdgcn_global_load_lds(
      (const __attribute__((address_space(1))) void*)g,
      (__attribute__((address_space(3))) void*)lds, 16, 0, 0);
}

// ---------------- scale reduction (deterministic) ----------------
__global__ void abs_sum_partial(const float* __restrict__ w, int n,
                                double* __restrict__ partial) {
  double s = 0.0;
  for (int i = blockIdx.x * 256 + threadIdx.x; i < n; i += 64 * 256)
    s += (double)fabsf(w[i]);
  __shared__ double sm[256];
  sm[threadIdx.x] = s;
  __syncthreads();
  for (int off = 128; off > 0; off >>= 1) {
    if (threadIdx.x < off) sm[threadIdx.x] += sm[threadIdx.x + off];
    __syncthreads();
  }
  if (threadIdx.x == 0) partial[blockIdx.x] = sm[0];
}

__global__ void finalize_scales(const double* __restrict__ partials,
                                float* __restrict__ scales) {
  if (threadIdx.x == 0 && blockIdx.x == 0) {
    const double counts[4] = {4194304.0, 1048576.0, 1048576.0, 4194304.0};
    for (int w = 0; w < 4; ++w) {
      double s = 0.0;
      for (int i = 0; i < 64; ++i) s += partials[w * 64 + i];
      float sc = (float)(s / counts[w]);
      scales[w] = fmaxf(sc, 1e-5f);
    }
  }
}

// ---------------- elementwise converts ----------------
__global__ void cvt_f32_bf16(const float* __restrict__ in, u16* __restrict__ out, int n4) {
  int i = blockIdx.x * 256 + threadIdx.x;
  if (i >= n4) return;
  float4 v = reinterpret_cast<const float4*>(in)[i];
  ushort4 o;
  o.x = f2bf(v.x); o.y = f2bf(v.y); o.z = f2bf(v.z); o.w = f2bf(v.w);
  reinterpret_cast<ushort4*>(out)[i] = o;
}

__global__ void sign_bf16(const float* __restrict__ in, u16* __restrict__ out, int n4) {
  int i = blockIdx.x * 256 + threadIdx.x;
  if (i >= n4) return;
  float4 v = reinterpret_cast<const float4*>(in)[i];
  ushort4 o;
  o.x = v.x > 0.f ? 0x3F80 : (v.x < 0.f ? 0xBF80 : 0);
  o.y = v.y > 0.f ? 0x3F80 : (v.y < 0.f ? 0xBF80 : 0);
  o.z = v.z > 0.f ? 0x3F80 : (v.z < 0.f ? 0xBF80 : 0);
  o.w = v.w > 0.f ? 0x3F80 : (v.w < 0.f ? 0xBF80 : 0);
  reinterpret_cast<ushort4*>(out)[i] = o;
}

// ---------------- GEMM: C[m,n] = scale * sum_k A[m,k]*Bt[n,k] ----------------
// A:[M,K] bf16, Bt:[N,K] bf16 (+/-1), C bf16 or f32. M,N mult 128, K mult 64.
template <int OUT_BF16>
__global__ __launch_bounds__(256, 2) void gemm_bt(
    const u16* __restrict__ A, const u16* __restrict__ Bt, void* __restrict__ Cv,
    const float* __restrict__ scale_ptr, int M, int N, int K) {
  __shared__ u16 lA[128 * 64];
  __shared__ u16 lB[128 * 64];
  const int tid = threadIdx.x;
  const int lane = tid & 63, wave = tid >> 6;
  const int lo = lane & 15, hi = lane >> 4;
  const int m0 = blockIdx.y * 128, n0 = blockIdx.x * 128;
  const int wr = (wave >> 1) * 64, wc = (wave & 1) * 64;

  f32x4 acc[4][4] = {};

  for (int k0 = 0; k0 < K; k0 += 64) {
#pragma unroll
    for (int it = 0; it < 4; ++it) {
      const int c = it * 256 + wave * 64 + lane;
      const int row = c >> 3, kc = (c & 7) << 3;
      lds_load16(&lA[(it * 256 + wave * 64) * 8], &A[(size_t)(m0 + row) * K + k0 + kc]);
      lds_load16(&lB[(it * 256 + wave * 64) * 8], &Bt[(size_t)(n0 + row) * K + k0 + kc]);
    }
    __syncthreads();
#pragma unroll
    for (int kk = 0; kk < 2; ++kk) {
      bf16x8 af[4], bfr[4];
#pragma unroll
      for (int i = 0; i < 4; ++i)
        af[i] = *reinterpret_cast<const bf16x8*>(&lA[(wr + i * 16 + lo) * 64 + kk * 32 + hi * 8]);
#pragma unroll
      for (int i = 0; i < 4; ++i)
        bfr[i] = *reinterpret_cast<const bf16x8*>(&lB[(wc + i * 16 + lo) * 64 + kk * 32 + hi * 8]);
#pragma unroll
      for (int mi = 0; mi < 4; ++mi)
#pragma unroll
        for (int ni = 0; ni < 4; ++ni)
          acc[mi][ni] = __builtin_amdgcn_mfma_f32_16x16x32_bf16(af[mi], bfr[ni], acc[mi][ni], 0, 0, 0);
    }
    __syncthreads();
  }

  const float scale = *scale_ptr;
#pragma unroll
  for (int mi = 0; mi < 4; ++mi) {
#pragma unroll
    for (int ni = 0; ni < 4; ++ni) {
#pragma unroll
      for (int r = 0; r < 4; ++r) {
        // C/D frag layout: col = lane&15, row = (lane>>4)*4 + r  [m89]
        const int row = m0 + wr + mi * 16 + hi * 4 + r;
        const int col = n0 + wc + ni * 16 + lo;
        const float v = acc[mi][ni][r] * scale;
        if (OUT_BF16)
          reinterpret_cast<u16*>(Cv)[(size_t)row * N + col] = f2bf(v);
        else
          reinterpret_cast<float*>(Cv)[(size_t)row * N + col] = v;
      }
    }
  }
}

// ---------------- flash attention (GQA, causal) ----------------
// grid: (S/64, 64).  blockIdx.y = b*32 + h;  h = kv*4+g.
// Q:[4096,2048], Kg/Vg:[4096,512], Og:[4096,2048] (all bf16 bits)
__global__ __launch_bounds__(256, 2) void flash_attn(
    const u16* __restrict__ Q, const u16* __restrict__ Kg,
    const u16* __restrict__ Vg, u16* __restrict__ Og) {
  __shared__ u16 lK[64 * 64];       // [t][d]
  __shared__ u16 lVt[64 * 72];      // [d][t], stride 72 keeps 16B align, ~2-way banks
  __shared__ u16 lP[4][16 * 72];    // per-wave P[q][t]

  const int tid = threadIdx.x;
  const int lane = tid & 63, wave = tid >> 6;
  const int lo = lane & 15, hi = lane >> 4;
  const int hy = blockIdx.y;
  const int b = hy >> 5, h = hy & 31, kv = h >> 2;
  const int q0 = blockIdx.x * 64;
  const int q0w = q0 + wave * 16;
  const int brow = b * S_LEN;
  const int kcol = kv * HD;

  // Q fragments live in registers for the whole block
  bf16x8 qf[2];
  {
    const int qr = brow + q0w + lo;
#pragma unroll
    for (int kk = 0; kk < 2; ++kk)
      qf[kk] = *reinterpret_cast<const bf16x8*>(
          &Q[(size_t)qr * D_MODEL + h * HD + kk * 32 + hi * 8]);
  }

  f32x4 oacc[4] = {};
  float m_run[4], l_run[4];
#pragma unroll
  for (int r = 0; r < 4; ++r) { m_run[r] = -1e30f; l_run[r] = 0.f; }

  const int nt = blockIdx.x + 1;
  for (int ti = 0; ti < nt; ++ti) {
    const int t0 = ti * 64;
    __syncthreads();  // prior tile's LDS reads complete before restage

    // K tile -> LDS linear [64][64] via direct async copy
#pragma unroll
    for (int it = 0; it < 2; ++it) {
      const int c = it * 256 + wave * 64 + lane;
      const int tr = c >> 3, kc = (c & 7) << 3;
      lds_load16(&lK[(it * 256 + wave * 64) * 8],
                 &Kg[(size_t)(brow + t0 + tr) * KV_DIM + kcol + kc]);
    }
    // V tile -> LDS transposed [d][t]; lane = t so ds_writes are conflict-free
    uint4 vv0 = *reinterpret_cast<const uint4*>(
        &Vg[(size_t)(brow + t0 + lane) * KV_DIM + kcol + wave * 8]);
    uint4 vv1 = *reinterpret_cast<const uint4*>(
        &Vg[(size_t)(brow + t0 + lane) * KV_DIM + kcol + (4 + wave) * 8]);
    {
      const unsigned* pw0 = reinterpret_cast<const unsigned*>(&vv0);
      const unsigned* pw1 = reinterpret_cast<const unsigned*>(&vv1);
#pragma unroll
      for (int j = 0; j < 4; ++j) {
        const int d0 = wave * 8 + 2 * j;
        lVt[(d0 + 0) * 72 + lane] = (u16)(pw0[j] & 0xffffu);
        lVt[(d0 + 1) * 72 + lane] = (u16)(pw0[j] >> 16);
        const int d1 = (4 + wave) * 8 + 2 * j;
        lVt[(d1 + 0) * 72 + lane] = (u16)(pw1[j] & 0xffffu);
        lVt[(d1 + 1) * 72 + lane] = (u16)(pw1[j] >> 16);
      }
    }
    __syncthreads();  // tiles ready (compiler drains vmcnt/lgkmcnt)

    // S = Q K^T  (A = Q rows, B[d][t] = lK[t][d])
    f32x4 sacc[4] = {};
#pragma unroll
    for (int kk = 0; kk < 2; ++kk) {
#pragma unroll
      for (int nf = 0; nf < 4; ++nf) {
        bf16x8 kf = *reinterpret_cast<const bf16x8*>(
            &lK[(nf * 16 + lo) * 64 + kk * 32 + hi * 8]);
        sacc[nf] = __builtin_amdgcn_mfma_f32_16x16x32_bf16(qf[kk], kf, sacc[nf], 0, 0, 0);
      }
    }

    // mask + scale + online softmax (rows are lane-group-local: q = hi*4+r)
    float p[4][4];
    float mt[4] = {-1e30f, -1e30f, -1e30f, -1e30f};
#pragma unroll
    for (int nf = 0; nf < 4; ++nf) {
      const int tg = t0 + nf * 16 + lo;
#pragma unroll
      for (int r = 0; r < 4; ++r) {
        const int qg = q0w + hi * 4 + r;
        float s = sacc[nf][r] * 0.125f;  // 1/sqrt(64)
        if (tg > qg) s = -1e30f;
        p[nf][r] = s;
        mt[r] = fmaxf(mt[r], s);
      }
    }
#pragma unroll
    for (int r = 0; r < 4; ++r) {
      float v = mt[r];
      v = fmaxf(v, __shfl_xor(v, 1));
      v = fmaxf(v, __shfl_xor(v, 2));
      v = fmaxf(v, __shfl_xor(v, 4));
      v = fmaxf(v, __shfl_xor(v, 8));
      const float mn = fmaxf(m_run[r], v);
      const float alpha = __expf(m_run[r] - mn);
      m_run[r] = mn;
      float rs = 0.f;
#pragma unroll
      for (int nf = 0; nf < 4; ++nf) {
        const float e = __expf(p[nf][r] - mn);
        p[nf][r] = e;
        rs += e;
      }
      rs += __shfl_xor(rs, 1);
      rs += __shfl_xor(rs, 2);
      rs += __shfl_xor(rs, 4);
      rs += __shfl_xor(rs, 8);
      l_run[r] = l_run[r] * alpha + rs;
#pragma unroll
      for (int nf = 0; nf < 4; ++nf) oacc[nf][r] *= alpha;
    }

    // P -> LDS (needs redistribution: PV A-frag wants row = lane&15)
#pragma unroll
    for (int nf = 0; nf < 4; ++nf)
#pragma unroll
      for (int r = 0; r < 4; ++r)
        lP[wave][(hi * 4 + r) * 72 + nf * 16 + lo] = f2bf(p[nf][r]);
    __syncthreads();

    // O += P V   (A = P[q][t], B[t][d] = lVt[d][t])
#pragma unroll
    for (int kk = 0; kk < 2; ++kk) {
      bf16x8 pf = *reinterpret_cast<const bf16x8*>(&lP[wave][lo * 72 + kk * 32 + hi * 8]);
#pragma unroll
      for (int nf = 0; nf < 4; ++nf) {
        bf16x8 vf = *reinterpret_cast<const bf16x8*>(
            &lVt[(nf * 16 + lo) * 72 + kk * 32 + hi * 8]);
        oacc[nf] = __builtin_amdgcn_mfma_f32_16x16x32_bf16(pf, vf, oacc[nf], 0, 0, 0);
      }
    }
  }

  float inv[4];
#pragma unroll
  for (int r = 0; r < 4; ++r) inv[r] = 1.f / l_run[r];
#pragma unroll
  for (int nf = 0; nf < 4; ++nf)
#pragma unroll
    for (int r = 0; r < 4; ++r)
      Og[(size_t)(brow + q0w + hi * 4 + r) * D_MODEL + h * HD + nf * 16 + lo] =
          f2bf(oacc[nf][r] * inv[r]);
}

// ---------------- launcher ----------------
extern "C" void kernel_launch(void* const* d_in, const int* in_sizes, int n_in,
                              void* d_out, int out_size, void* d_ws, size_t ws_size,
                              hipStream_t stream) {
  (void)in_sizes; (void)n_in; (void)out_size; (void)ws_size;
  const float* x  = (const float*)d_in[0];
  const float* wq = (const float*)d_in[1];
  const float* wk = (const float*)d_in[2];
  const float* wv = (const float*)d_in[3];
  const float* wo = (const float*)d_in[4];
  float* out = (float*)d_out;
  char* ws = (char*)d_ws;

  double* partials = (double*)ws;            // 2048 B
  float* scales = (float*)(ws + 2048);       // 16 B
  size_t off = 4096;
  u16* xb  = (u16*)(ws + off); off += (size_t)MROWS * D_MODEL * 2;
  u16* wqs = (u16*)(ws + off); off += (size_t)D_MODEL * D_MODEL * 2;
  u16* wks = (u16*)(ws + off); off += (size_t)KV_DIM * D_MODEL * 2;
  u16* wvs = (u16*)(ws + off); off += (size_t)KV_DIM * D_MODEL * 2;
  u16* wos = (u16*)(ws + off); off += (size_t)D_MODEL * D_MODEL * 2;
  u16* qb  = (u16*)(ws + off); off += (size_t)MROWS * D_MODEL * 2;
  u16* kb  = (u16*)(ws + off); off += (size_t)MROWS * KV_DIM * 2;
  u16* vb  = (u16*)(ws + off); off += (size_t)MROWS * KV_DIM * 2;
  u16* ao  = (u16*)(ws + off); off += (size_t)MROWS * D_MODEL * 2;

  // 1. per-tensor |w| means (deterministic 2-pass)
  abs_sum_partial<<<64, 256, 0, stream>>>(wq, D_MODEL * D_MODEL, partials + 0);
  abs_sum_partial<<<64, 256, 0, stream>>>(wk, KV_DIM * D_MODEL, partials + 64);
  abs_sum_partial<<<64, 256, 0, stream>>>(wv, KV_DIM * D_MODEL, partials + 128);
  abs_sum_partial<<<64, 256, 0, stream>>>(wo, D_MODEL * D_MODEL, partials + 192);
  finalize_scales<<<1, 64, 0, stream>>>(partials, scales);

  // 2. dtype prep
  cvt_f32_bf16<<<MROWS * D_MODEL / 4 / 256, 256, 0, stream>>>(x, xb, MROWS * D_MODEL / 4);
  sign_bf16<<<D_MODEL * D_MODEL / 4 / 256, 256, 0, stream>>>(wq, wqs, D_MODEL * D_MODEL / 4);
  sign_bf16<<<KV_DIM * D_MODEL / 4 / 256, 256, 0, stream>>>(wk, wks, KV_DIM * D_MODEL / 4);
  sign_bf16<<<KV_DIM * D_MODEL / 4 / 256, 256, 0, stream>>>(wv, wvs, KV_DIM * D_MODEL / 4);
  sign_bf16<<<D_MODEL * D_MODEL / 4 / 256, 256, 0, stream>>>(wo, wos, D_MODEL * D_MODEL / 4);

  // 3. projections (scale folded in epilogue, outputs bf16)
  gemm_bt<1><<<dim3(D_MODEL / 128, MROWS / 128), 256, 0, stream>>>(
      xb, wqs, qb, scales + 0, MROWS, D_MODEL, D_MODEL);
  gemm_bt<1><<<dim3(KV_DIM / 128, MROWS / 128), 256, 0, stream>>>(
      xb, wks, kb, scales + 1, MROWS, KV_DIM, D_MODEL);
  gemm_bt<1><<<dim3(KV_DIM / 128, MROWS / 128), 256, 0, stream>>>(
      xb, wvs, vb, scales + 2, MROWS, KV_DIM, D_MODEL);

  // 4. GQA causal flash attention
  flash_attn<<<dim3(S_LEN / 64, 64), 256, 0, stream>>>(qb, kb, vb, ao);

  // 5. output projection (f32 out)
  gemm_bt<0><<<dim3(D_MODEL / 128, MROWS / 128), 256, 0, stream>>>(
      ao, wos, out, scales + 3, MROWS, D_MODEL, D_MODEL);
}

// Round 2
// 415.113 us; speedup vs baseline: 1.5129x; 1.5129x over previous
//
#include <hip/hip_runtime.h>
#include <stdint.h>

// ---------------------------------------------------------------------------
// BitAttention round 2:
//   - sign+abs fused weight prep (one pass over each weight)
//   - fused QKV projection GEMM (N=3072), per-column-block scale table
//   - flash_attn v2: 128 q-rows/block, XOR-swizzled K tile, 2 barriers/tile,
//     block-uniform mask skip, setprio around MFMA
// ws layout (bytes):
//   [0,2048)    double partials[256]  (wq,wk,wv,wo x 64)
//   [2048,2208) float tabs[40]: [0..23] qkv col-block scales, [24..39] o
//   [4096,...)  xb(16M) wqkvs(12M) wos(8M) qkvb(24M) ao(16M)
// ---------------------------------------------------------------------------

#define D_MODEL 2048
#define S_LEN   2048
#define BATCH   2
#define NKV     8
#define HD      64
#define MROWS   (BATCH * S_LEN)   // 4096
#define NQKV    3072              // 2048 Q + 512 K + 512 V

typedef unsigned short u16;
typedef __bf16 bf16x8 __attribute__((ext_vector_type(8)));
typedef float  f32x4  __attribute__((ext_vector_type(4)));

__device__ __forceinline__ u16 f2bf(float f) {
  union { float f; unsigned u; } v; v.f = f;
  unsigned r = v.u + 0x7FFFu + ((v.u >> 16) & 1u);   // RNE
  return (u16)(r >> 16);
}

__device__ __forceinline__ void lds_load16(u16* lds, const u16* g) {
  __builtin_amdgcn_global_load_lds(
      (const __attribute__((address_space(1))) void*)g,
      (__attribute__((address_space(3))) void*)lds, 16, 0, 0);
}

// ---------------- fused sign + |w| partial sum ----------------
__global__ void sign_abs(const float* __restrict__ in, u16* __restrict__ out,
                         int n4, double* __restrict__ partial) {
  double s = 0.0;
  for (int i = blockIdx.x * 256 + threadIdx.x; i < n4; i += 64 * 256) {
    float4 v = reinterpret_cast<const float4*>(in)[i];
    ushort4 o;
    o.x = v.x > 0.f ? 0x3F80 : (v.x < 0.f ? 0xBF80 : 0);
    o.y = v.y > 0.f ? 0x3F80 : (v.y < 0.f ? 0xBF80 : 0);
    o.z = v.z > 0.f ? 0x3F80 : (v.z < 0.f ? 0xBF80 : 0);
    o.w = v.w > 0.f ? 0x3F80 : (v.w < 0.f ? 0xBF80 : 0);
    reinterpret_cast<ushort4*>(out)[i] = o;
    s += (double)fabsf(v.x) + (double)fabsf(v.y) +
         (double)fabsf(v.z) + (double)fabsf(v.w);
  }
  __shared__ double sm[256];
  sm[threadIdx.x] = s;
  __syncthreads();
  for (int off = 128; off > 0; off >>= 1) {
    if (threadIdx.x < off) sm[threadIdx.x] += sm[threadIdx.x + off];
    __syncthreads();
  }
  if (threadIdx.x == 0) partial[blockIdx.x] = sm[0];
}

__global__ void finalize_scales(const double* __restrict__ partials,
                                float* __restrict__ tabs) {
  if (threadIdx.x == 0 && blockIdx.x == 0) {
    const double counts[4] = {4194304.0, 1048576.0, 1048576.0, 4194304.0};
    float sc[4];
    for (int w = 0; w < 4; ++w) {
      double s = 0.0;
      for (int i = 0; i < 64; ++i) s += partials[w * 64 + i];
      sc[w] = fmaxf((float)(s / counts[w]), 1e-5f);
    }
    for (int i = 0; i < 24; ++i) tabs[i] = (i < 16) ? sc[0] : (i < 20 ? sc[1] : sc[2]);
    for (int i = 0; i < 16; ++i) tabs[24 + i] = sc[3];
  }
}

__global__ void cvt_f32_bf16(const float* __restrict__ in, u16* __restrict__ out, int n4) {
  int i = blockIdx.x * 256 + threadIdx.x;
  if (i >= n4) return;
  float4 v = reinterpret_cast<const float4*>(in)[i];
  ushort4 o;
  o.x = f2bf(v.x); o.y = f2bf(v.y); o.z = f2bf(v.z); o.w = f2bf(v.w);
  reinterpret_cast<ushort4*>(out)[i] = o;
}

// ---------------- GEMM: C[m,n] = tab[bx] * sum_k A[m,k]*Bt[n,k] ----------------
template <int OUT_BF16>
__global__ __launch_bounds__(256, 2) void gemm_bt(
    const u16* __restrict__ A, const u16* __restrict__ Bt, void* __restrict__ Cv,
    const float* __restrict__ tab, int M, int N, int K) {
  __shared__ u16 lA[128 * 64];
  __shared__ u16 lB[128 * 64];
  const int tid = threadIdx.x;
  const int lane = tid & 63, wave = tid >> 6;
  const int lo = lane & 15, hi = lane >> 4;
  const int m0 = blockIdx.y * 128, n0 = blockIdx.x * 128;
  const int wr = (wave >> 1) * 64, wc = (wave & 1) * 64;

  f32x4 acc[4][4] = {};

  for (int k0 = 0; k0 < K; k0 += 64) {
#pragma unroll
    for (int it = 0; it < 4; ++it) {
      const int c = it * 256 + wave * 64 + lane;
      const int row = c >> 3, kc = (c & 7) << 3;
      lds_load16(&lA[(it * 256 + wave * 64) * 8], &A[(size_t)(m0 + row) * K + k0 + kc]);
      lds_load16(&lB[(it * 256 + wave * 64) * 8], &Bt[(size_t)(n0 + row) * K + k0 + kc]);
    }
    __syncthreads();
#pragma unroll
    for (int kk = 0; kk < 2; ++kk) {
      bf16x8 af[4], bfr[4];
#pragma unroll
      for (int i = 0; i < 4; ++i)
        af[i] = *reinterpret_cast<const bf16x8*>(&lA[(wr + i * 16 + lo) * 64 + kk * 32 + hi * 8]);
#pragma unroll
      for (int i = 0; i < 4; ++i)
        bfr[i] = *reinterpret_cast<const bf16x8*>(&lB[(wc + i * 16 + lo) * 64 + kk * 32 + hi * 8]);
#pragma unroll
      for (int mi = 0; mi < 4; ++mi)
#pragma unroll
        for (int ni = 0; ni < 4; ++ni)
          acc[mi][ni] = __builtin_amdgcn_mfma_f32_16x16x32_bf16(af[mi], bfr[ni], acc[mi][ni], 0, 0, 0);
    }
    __syncthreads();
  }

  const float scale = tab[blockIdx.x];
#pragma unroll
  for (int mi = 0; mi < 4; ++mi) {
#pragma unroll
    for (int ni = 0; ni < 4; ++ni) {
#pragma unroll
      for (int r = 0; r < 4; ++r) {
        const int row = m0 + wr + mi * 16 + hi * 4 + r;
        const int col = n0 + wc + ni * 16 + lo;
        const float v = acc[mi][ni][r] * scale;
        if (OUT_BF16)
          reinterpret_cast<u16*>(Cv)[(size_t)row * N + col] = f2bf(v);
        else
          reinterpret_cast<float*>(Cv)[(size_t)row * N + col] = v;
      }
    }
  }
}

// ---------------- flash attention v2 (GQA, causal) ----------------
// grid: (S/128, 64).  blockIdx.y = b*32+h, h = kv*4+g.
// QKV:[4096][3072] bf16 (Q cols 0..2047, K 2048..2559, V 2560..3071)
#define LDQKV 3072
__global__ __launch_bounds__(256, 3) void flash_attn(
    const u16* __restrict__ QKV, u16* __restrict__ Og) {
  __shared__ u16 lK[64 * 64];       // XOR-swizzled: chunk ^= row&7
  __shared__ u16 lVt[64 * 72];      // [d][t], stride 72 (2-way banks, free)
  __shared__ u16 lP[4][32 * 72];    // per-wave P[q][t]

  const int tid = threadIdx.x;
  const int lane = tid & 63, wave = tid >> 6;
  const int lo = lane & 15, hi = lane >> 4;
  const int hy = blockIdx.y;
  const int b = hy >> 5, h = hy & 31, kv = h >> 2;
  const int q0 = blockIdx.x * 128;
  const int q0w = q0 + wave * 32;
  const int brow = b * S_LEN;
  const u16* Q  = QKV + h * HD;
  const u16* Kg = QKV + 2048 + kv * HD;
  const u16* Vg = QKV + 2560 + kv * HD;

  // Q fragments: 2 m-frags x 2 k-halves, resident all block
  bf16x8 qf[2][2];
#pragma unroll
  for (int mi = 0; mi < 2; ++mi) {
    const size_t qr = (size_t)(brow + q0w + mi * 16 + lo) * LDQKV;
#pragma unroll
    for (int kk = 0; kk < 2; ++kk)
      qf[mi][kk] = *reinterpret_cast<const bf16x8*>(&Q[qr + kk * 32 + hi * 8]);
  }

  f32x4 oacc[2][4] = {};
  float m_run[2][4], l_run[2][4];
#pragma unroll
  for (int mi = 0; mi < 2; ++mi)
#pragma unroll
    for (int r = 0; r < 4; ++r) { m_run[mi][r] = -1e30f; l_run[mi][r] = 0.f; }

  const int nt = 2 * blockIdx.x + 2;
  const int swl = (lo & 7) << 3;    // read-side swizzle for lK (elems)

  for (int ti = 0; ti < nt; ++ti) {
    const int t0 = ti * 64;

    // ---- stage K (swizzled source -> linear LDS dest; rule #21) ----
#pragma unroll
    for (int it = 0; it < 2; ++it) {
      const int c = it * 256 + tid;
      const int row = c >> 3;
      const int ch = (c & 7) ^ (row & 7);
      lds_load16(&lK[(it * 256 + wave * 64) * 8],
                 &Kg[(size_t)(brow + t0 + row) * LDQKV + ch * 8]);
    }
    // ---- stage V transposed [d][t] via registers (lane = t) ----
    {
      const size_t vr = (size_t)(brow + t0 + lane) * LDQKV;
      uint4 vv0 = *reinterpret_cast<const uint4*>(&Vg[vr + wave * 8]);
      uint4 vv1 = *reinterpret_cast<const uint4*>(&Vg[vr + (4 + wave) * 8]);
      const unsigned* pw0 = reinterpret_cast<const unsigned*>(&vv0);
      const unsigned* pw1 = reinterpret_cast<const unsigned*>(&vv1);
#pragma unroll
      for (int j = 0; j < 4; ++j) {
        const int d0 = wave * 8 + 2 * j;
        lVt[(d0 + 0) * 72 + lane] = (u16)(pw0[j] & 0xffffu);
        lVt[(d0 + 1) * 72 + lane] = (u16)(pw0[j] >> 16);
        const int d1 = (4 + wave) * 8 + 2 * j;
        lVt[(d1 + 0) * 72 + lane] = (u16)(pw1[j] & 0xffffu);
        lVt[(d1 + 1) * 72 + lane] = (u16)(pw1[j] >> 16);
      }
    }
    __syncthreads();   // tiles visible (vmcnt+lgkmcnt drained by barrier)

    // ---- S = Q K^T ----
    f32x4 sacc[2][4] = {};
    __builtin_amdgcn_s_setprio(1);
#pragma unroll
    for (int kk = 0; kk < 2; ++kk) {
#pragma unroll
      for (int nf = 0; nf < 4; ++nf) {
        const int row = nf * 16 + lo;
        bf16x8 kf = *reinterpret_cast<const bf16x8*>(
            &lK[row * 64 + ((kk * 32 + hi * 8) ^ swl)]);
#pragma unroll
        for (int mi = 0; mi < 2; ++mi)
          sacc[mi][nf] = __builtin_amdgcn_mfma_f32_16x16x32_bf16(
              qf[mi][kk], kf, sacc[mi][nf], 0, 0, 0);
      }
    }
    __builtin_amdgcn_s_setprio(0);

    // ---- online softmax (rows lane-group-local: q = mi*16 + hi*4 + r) ----
    const bool full = (t0 + 64 <= q0);   // block-uniform: no masking needed
#pragma unroll
    for (int mi = 0; mi < 2; ++mi) {
      float p[4][4];
      float mt[4] = {-1e30f, -1e30f, -1e30f, -1e30f};
#pragma unroll
      for (int nf = 0; nf < 4; ++nf) {
        const int tg = t0 + nf * 16 + lo;
#pragma unroll
        for (int r = 0; r < 4; ++r) {
          float s = sacc[mi][nf][r] * 0.125f;   // 1/sqrt(64)
          if (!full) {
            const int qg = q0w + mi * 16 + hi * 4 + r;
            if (tg > qg) s = -1e30f;
          }
          p[nf][r] = s;
          mt[r] = fmaxf(mt[r], s);
        }
      }
#pragma unroll
      for (int r = 0; r < 4; ++r) {
        float v = mt[r];
        v = fmaxf(v, __shfl_xor(v, 1));
        v = fmaxf(v, __shfl_xor(v, 2));
        v = fmaxf(v, __shfl_xor(v, 4));
        v = fmaxf(v, __shfl_xor(v, 8));
        const float mn = fmaxf(m_run[mi][r], v);
        const float alpha = __expf(m_run[mi][r] - mn);
        m_run[mi][r] = mn;
        float rs = 0.f;
#pragma unroll
        for (int nf = 0; nf < 4; ++nf) {
          const float e = __expf(p[nf][r] - mn);
          p[nf][r] = e;
          rs += e;
        }
        rs += __shfl_xor(rs, 1);
        rs += __shfl_xor(rs, 2);
        rs += __shfl_xor(rs, 4);
        rs += __shfl_xor(rs, 8);
        l_run[mi][r] = l_run[mi][r] * alpha + rs;
#pragma unroll
        for (int nf = 0; nf < 4; ++nf) oacc[mi][nf][r] *= alpha;
      }
      // P -> wave-private LDS (redistribute to A-frag layout; no barrier)
#pragma unroll
      for (int nf = 0; nf < 4; ++nf)
#pragma unroll
        for (int r = 0; r < 4; ++r)
          lP[wave][(mi * 16 + hi * 4 + r) * 72 + nf * 16 + lo] = f2bf(p[nf][r]);
    }

    // ---- O += P V ----
    __builtin_amdgcn_s_setprio(1);
#pragma unroll
    for (int kk = 0; kk < 2; ++kk) {
      bf16x8 pf[2];
#pragma unroll
      for (int mi = 0; mi < 2; ++mi)
        pf[mi] = *reinterpret_cast<const bf16x8*>(
            &lP[wave][(mi * 16 + lo) * 72 + kk * 32 + hi * 8]);
#pragma unroll
      for (int nf = 0; nf < 4; ++nf) {
        bf16x8 vf = *reinterpret_cast<const bf16x8*>(
            &lVt[(nf * 16 + lo) * 72 + kk * 32 + hi * 8]);
#pragma unroll
        for (int mi = 0; mi < 2; ++mi)
          oacc[mi][nf] = __builtin_amdgcn_mfma_f32_16x16x32_bf16(
              pf[mi], vf, oacc[mi][nf], 0, 0, 0);
      }
    }
    __builtin_amdgcn_s_setprio(0);
    __syncthreads();   // all reads done before next tile's restage
  }

#pragma unroll
  for (int mi = 0; mi < 2; ++mi) {
    float inv[4];
#pragma unroll
    for (int r = 0; r < 4; ++r) inv[r] = 1.f / l_run[mi][r];
#pragma unroll
    for (int nf = 0; nf < 4; ++nf)
#pragma unroll
      for (int r = 0; r < 4; ++r)
        Og[(size_t)(brow + q0w + mi * 16 + hi * 4 + r) * D_MODEL +
           h * HD + nf * 16 + lo] = f2bf(oacc[mi][nf][r] * inv[r]);
  }
}

// ---------------- launcher ----------------
extern "C" void kernel_launch(void* const* d_in, const int* in_sizes, int n_in,
                              void* d_out, int out_size, void* d_ws, size_t ws_size,
                              hipStream_t stream) {
  (void)in_sizes; (void)n_in; (void)out_size; (void)ws_size;
  const float* x  = (const float*)d_in[0];
  const float* wq = (const float*)d_in[1];
  const float* wk = (const float*)d_in[2];
  const float* wv = (const float*)d_in[3];
  const float* wo = (const float*)d_in[4];
  float* out = (float*)d_out;
  char* ws = (char*)d_ws;

  double* partials = (double*)ws;            // 2048 B
  float* tabs = (float*)(ws + 2048);         // 40 floats
  size_t off = 4096;
  u16* xb    = (u16*)(ws + off); off += (size_t)MROWS * D_MODEL * 2;
  u16* wqkvs = (u16*)(ws + off); off += (size_t)NQKV * D_MODEL * 2;
  u16* wos   = (u16*)(ws + off); off += (size_t)D_MODEL * D_MODEL * 2;
  u16* qkvb  = (u16*)(ws + off); off += (size_t)MROWS * NQKV * 2;
  u16* ao    = (u16*)(ws + off); off += (size_t)MROWS * D_MODEL * 2;

  // 1. weight prep: sign into concat buffer + |w| partial sums (one pass)
  sign_abs<<<64, 256, 0, stream>>>(wq, wqkvs,                     D_MODEL * D_MODEL / 4, partials + 0);
  sign_abs<<<64, 256, 0, stream>>>(wk, wqkvs + 2048 * D_MODEL,    512 * D_MODEL / 4,     partials + 64);
  sign_abs<<<64, 256, 0, stream>>>(wv, wqkvs + 2560 * D_MODEL,    512 * D_MODEL / 4,     partials + 128);
  sign_abs<<<64, 256, 0, stream>>>(wo, wos,                       D_MODEL * D_MODEL / 4, partials + 192);
  finalize_scales<<<1, 64, 0, stream>>>(partials, tabs);

  // 2. x -> bf16
  cvt_f32_bf16<<<MROWS * D_MODEL / 4 / 256, 256, 0, stream>>>(x, xb, MROWS * D_MODEL / 4);

  // 3. fused QKV projection (N = 3072)
  gemm_bt<1><<<dim3(NQKV / 128, MROWS / 128), 256, 0, stream>>>(
      xb, wqkvs, qkvb, tabs, MROWS, NQKV, D_MODEL);

  // 4. GQA causal flash attention
  flash_attn<<<dim3(S_LEN / 128, 64), 256, 0, stream>>>(qkvb, ao);

  // 5. output projection (f32 out)
  gemm_bt<0><<<dim3(D_MODEL / 128, MROWS / 128), 256, 0, stream>>>(
      ao, wos, out, tabs + 24, MROWS, D_MODEL, D_MODEL);
}

// Round 3
// 224.395 us; speedup vs baseline: 2.7988x; 1.8499x over previous
//
#include <hip/hip_runtime.h>
#include <stdint.h>

// ---------------------------------------------------------------------------
// BitAttention round 3:
//   - flash_attn v3: work-balanced q-tile pairing (grid 8x64, constant 34
//     tile-units/block), double-buffered K/V with 1 barrier/tile, defer-max
//     (THR=8), lazy l-reduction (epilogue-only), P->bf16 by truncation
//   - prep_weights: all 4 sign+|w| passes fused into one 640-block kernel
//   - GEMMs unchanged (m97-structure 128^2)
// ws layout (bytes):
//   [0,5120)    double partials[640]
//   [6144,6304) float tabs[40]: [0..23] qkv col-block scales, [24..39] o
//   [8192,...)  xb(16M) wqkvs(12M) wos(8M) qkvb(24M) ao(16M)
// ---------------------------------------------------------------------------

#define D_MODEL 2048
#define S_LEN   2048
#define BATCH   2
#define NKV     8
#define HD      64
#define MROWS   (BATCH * S_LEN)   // 4096
#define NQKV    3072              // 2048 Q + 512 K + 512 V
#define LDQKV   3072

typedef unsigned short u16;
typedef __bf16 bf16x8 __attribute__((ext_vector_type(8)));
typedef float  f32x4  __attribute__((ext_vector_type(4)));

__device__ __forceinline__ u16 f2bf(float f) {
  union { float f; unsigned u; } v; v.f = f;
  unsigned r = v.u + 0x7FFFu + ((v.u >> 16) & 1u);   // RNE
  return (u16)(r >> 16);
}

__device__ __forceinline__ u16 f2bf_trunc(float f) {
  union { float f; unsigned u; } v; v.f = f;
  return (u16)(v.u >> 16);
}

__device__ __forceinline__ void lds_load16(u16* lds, const u16* g) {
  __builtin_amdgcn_global_load_lds(
      (const __attribute__((address_space(1))) void*)g,
      (__attribute__((address_space(3))) void*)lds, 16, 0, 0);
}

// ---------------- fused weight prep: sign + |w| partial sums ----------------
// grid 640: [0,256)=wq, [256,320)=wk, [320,384)=wv, [384,640)=wo
__global__ void prep_weights(const float* __restrict__ wq, const float* __restrict__ wk,
                             const float* __restrict__ wv, const float* __restrict__ wo,
                             u16* __restrict__ wqkvs, u16* __restrict__ wos,
                             double* __restrict__ partials) {
  const int bid = blockIdx.x;
  const float* src; u16* dst; int n4, rb, nb;
  if (bid < 256)      { src = wq; dst = wqkvs;                  n4 = 1048576; rb = bid;       nb = 256; }
  else if (bid < 320) { src = wk; dst = wqkvs + 2048 * D_MODEL; n4 = 262144;  rb = bid - 256; nb = 64;  }
  else if (bid < 384) { src = wv; dst = wqkvs + 2560 * D_MODEL; n4 = 262144;  rb = bid - 320; nb = 64;  }
  else                { src = wo; dst = wos;                    n4 = 1048576; rb = bid - 384; nb = 256; }
  double s = 0.0;
  for (int i = rb * 256 + threadIdx.x; i < n4; i += nb * 256) {
    float4 v = reinterpret_cast<const float4*>(src)[i];
    ushort4 o;
    o.x = v.x > 0.f ? 0x3F80 : (v.x < 0.f ? 0xBF80 : 0);
    o.y = v.y > 0.f ? 0x3F80 : (v.y < 0.f ? 0xBF80 : 0);
    o.z = v.z > 0.f ? 0x3F80 : (v.z < 0.f ? 0xBF80 : 0);
    o.w = v.w > 0.f ? 0x3F80 : (v.w < 0.f ? 0xBF80 : 0);
    reinterpret_cast<ushort4*>(dst)[i] = o;
    s += (double)fabsf(v.x) + (double)fabsf(v.y) +
         (double)fabsf(v.z) + (double)fabsf(v.w);
  }
  __shared__ double sm[256];
  sm[threadIdx.x] = s;
  __syncthreads();
  for (int off = 128; off > 0; off >>= 1) {
    if (threadIdx.x < off) sm[threadIdx.x] += sm[threadIdx.x + off];
    __syncthreads();
  }
  if (threadIdx.x == 0) partials[bid] = sm[0];
}

__global__ void finalize_scales(const double* __restrict__ partials,
                                float* __restrict__ tabs) {
  if (threadIdx.x == 0 && blockIdx.x == 0) {
    const int beg[4] = {0, 256, 320, 384};
    const int end[4] = {256, 320, 384, 640};
    const double counts[4] = {4194304.0, 1048576.0, 1048576.0, 4194304.0};
    float sc[4];
    for (int w = 0; w < 4; ++w) {
      double s = 0.0;
      for (int i = beg[w]; i < end[w]; ++i) s += partials[i];
      sc[w] = fmaxf((float)(s / counts[w]), 1e-5f);
    }
    for (int i = 0; i < 24; ++i) tabs[i] = (i < 16) ? sc[0] : (i < 20 ? sc[1] : sc[2]);
    for (int i = 0; i < 16; ++i) tabs[24 + i] = sc[3];
  }
}

__global__ void cvt_f32_bf16(const float* __restrict__ in, u16* __restrict__ out, int n4) {
  int i = blockIdx.x * 256 + threadIdx.x;
  if (i >= n4) return;
  float4 v = reinterpret_cast<const float4*>(in)[i];
  ushort4 o;
  o.x = f2bf(v.x); o.y = f2bf(v.y); o.z = f2bf(v.z); o.w = f2bf(v.w);
  reinterpret_cast<ushort4*>(out)[i] = o;
}

// ---------------- GEMM: C[m,n] = tab[bx] * sum_k A[m,k]*Bt[n,k] ----------------
template <int OUT_BF16>
__global__ __launch_bounds__(256, 2) void gemm_bt(
    const u16* __restrict__ A, const u16* __restrict__ Bt, void* __restrict__ Cv,
    const float* __restrict__ tab, int M, int N, int K) {
  __shared__ u16 lA[128 * 64];
  __shared__ u16 lB[128 * 64];
  const int tid = threadIdx.x;
  const int lane = tid & 63, wave = tid >> 6;
  const int lo = lane & 15, hi = lane >> 4;
  const int m0 = blockIdx.y * 128, n0 = blockIdx.x * 128;
  const int wr = (wave >> 1) * 64, wc = (wave & 1) * 64;

  f32x4 acc[4][4] = {};

  for (int k0 = 0; k0 < K; k0 += 64) {
#pragma unroll
    for (int it = 0; it < 4; ++it) {
      const int c = it * 256 + wave * 64 + lane;
      const int row = c >> 3, kc = (c & 7) << 3;
      lds_load16(&lA[(it * 256 + wave * 64) * 8], &A[(size_t)(m0 + row) * K + k0 + kc]);
      lds_load16(&lB[(it * 256 + wave * 64) * 8], &Bt[(size_t)(n0 + row) * K + k0 + kc]);
    }
    __syncthreads();
#pragma unroll
    for (int kk = 0; kk < 2; ++kk) {
      bf16x8 af[4], bfr[4];
#pragma unroll
      for (int i = 0; i < 4; ++i)
        af[i] = *reinterpret_cast<const bf16x8*>(&lA[(wr + i * 16 + lo) * 64 + kk * 32 + hi * 8]);
#pragma unroll
      for (int i = 0; i < 4; ++i)
        bfr[i] = *reinterpret_cast<const bf16x8*>(&lB[(wc + i * 16 + lo) * 64 + kk * 32 + hi * 8]);
#pragma unroll
      for (int mi = 0; mi < 4; ++mi)
#pragma unroll
        for (int ni = 0; ni < 4; ++ni)
          acc[mi][ni] = __builtin_amdgcn_mfma_f32_16x16x32_bf16(af[mi], bfr[ni], acc[mi][ni], 0, 0, 0);
    }
    __syncthreads();
  }

  const float scale = tab[blockIdx.x];
#pragma unroll
  for (int mi = 0; mi < 4; ++mi) {
#pragma unroll
    for (int ni = 0; ni < 4; ++ni) {
#pragma unroll
      for (int r = 0; r < 4; ++r) {
        const int row = m0 + wr + mi * 16 + hi * 4 + r;
        const int col = n0 + wc + ni * 16 + lo;
        const float v = acc[mi][ni][r] * scale;
        if (OUT_BF16)
          reinterpret_cast<u16*>(Cv)[(size_t)row * N + col] = f2bf(v);
        else
          reinterpret_cast<float*>(Cv)[(size_t)row * N + col] = v;
      }
    }
  }
}

// ---------------- flash attention v3 (GQA, causal, balanced) ----------------
// grid: (8, 64).  blockIdx.y = b*32+h;  block does q-tiles bx and 15-bx.
__device__ __forceinline__ void stage_k(u16* dst, const u16* Kg, int rowbase,
                                        int tid, int wave) {
#pragma unroll
  for (int it = 0; it < 2; ++it) {
    const int c = it * 256 + tid;
    const int row = c >> 3;
    const int ch = (c & 7) ^ (row & 7);   // pre-swizzled source (rule #21)
    lds_load16(dst + (it * 256 + wave * 64) * 8,
               Kg + (size_t)(rowbase + row) * LDQKV + ch * 8);
  }
}

__device__ __forceinline__ void load_v(const u16* Vg, int rowbase, int lane, int wave,
                                       uint4& a, uint4& b) {
  const size_t vr = (size_t)(rowbase + lane) * LDQKV;
  a = *reinterpret_cast<const uint4*>(Vg + vr + wave * 8);
  b = *reinterpret_cast<const uint4*>(Vg + vr + (4 + wave) * 8);
}

__device__ __forceinline__ void write_v(u16* lVt, int lane, int wave,
                                        const uint4& a, const uint4& b) {
  const unsigned* pw0 = reinterpret_cast<const unsigned*>(&a);
  const unsigned* pw1 = reinterpret_cast<const unsigned*>(&b);
#pragma unroll
  for (int j = 0; j < 4; ++j) {
    const int d0 = wave * 8 + 2 * j;
    lVt[(d0 + 0) * 72 + lane] = (u16)(pw0[j] & 0xffffu);
    lVt[(d0 + 1) * 72 + lane] = (u16)(pw0[j] >> 16);
    const int d1 = (4 + wave) * 8 + 2 * j;
    lVt[(d1 + 0) * 72 + lane] = (u16)(pw1[j] & 0xffffu);
    lVt[(d1 + 1) * 72 + lane] = (u16)(pw1[j] >> 16);
  }
}

__global__ __launch_bounds__(256, 2) void flash_attn(
    const u16* __restrict__ QKV, u16* __restrict__ Og) {
  __shared__ u16 lK[2][64 * 64];    // XOR-swizzled chunks
  __shared__ u16 lVt[2][64 * 72];   // [d][t]
  __shared__ u16 lP[4][32 * 72];    // per-wave P[q][t]

  const int tid = threadIdx.x;
  const int lane = tid & 63, wave = tid >> 6;
  const int lo = lane & 15, hi = lane >> 4;
  const int hy = blockIdx.y;
  const int b = hy >> 5, h = hy & 31, kv = h >> 2;
  const int brow = b * S_LEN;
  const u16* Q  = QKV + h * HD;
  const u16* Kg = QKV + 2048 + kv * HD;
  const u16* Vg = QKV + 2560 + kv * HD;
  const int swl = (lo & 7) << 3;

#pragma unroll 1
  for (int pi = 0; pi < 2; ++pi) {
    const int qt = pi == 0 ? (int)blockIdx.x : (15 - (int)blockIdx.x);
    const int q0 = qt * 128;
    const int q0w = q0 + wave * 32;
    const int nt = 2 * qt + 2;

    // Q fragments resident for the pass
    bf16x8 qf[2][2];
#pragma unroll
    for (int mi = 0; mi < 2; ++mi) {
      const size_t qr = (size_t)(brow + q0w + mi * 16 + lo) * LDQKV;
#pragma unroll
      for (int kk = 0; kk < 2; ++kk)
        qf[mi][kk] = *reinterpret_cast<const bf16x8*>(&Q[qr + kk * 32 + hi * 8]);
    }

    f32x4 oacc[2][4] = {};
    float m_run[2][4], l_lane[2][4];
#pragma unroll
    for (int mi = 0; mi < 2; ++mi)
#pragma unroll
      for (int r = 0; r < 4; ++r) { m_run[mi][r] = -1e30f; l_lane[mi][r] = 0.f; }

    // prologue: stage tile 0 into buffer 0
    stage_k(lK[0], Kg, brow, tid, wave);
    {
      uint4 va, vb;
      load_v(Vg, brow, lane, wave, va, vb);
      write_v(lVt[0], lane, wave, va, vb);
    }
    __syncthreads();

#pragma unroll 1
    for (int ti = 0; ti < nt; ++ti) {
      const int t0 = ti * 64;
      const int cur = ti & 1;
      u16* lKc = (u16*)lK[cur];
      u16* lVc = (u16*)lVt[cur];

      // ---- S = Q K^T ----
      f32x4 sacc[2][4] = {};
      __builtin_amdgcn_s_setprio(1);
#pragma unroll
      for (int kk = 0; kk < 2; ++kk) {
#pragma unroll
        for (int nf = 0; nf < 4; ++nf) {
          bf16x8 kf = *reinterpret_cast<const bf16x8*>(
              &lKc[(nf * 16 + lo) * 64 + ((kk * 32 + hi * 8) ^ swl)]);
#pragma unroll
          for (int mi = 0; mi < 2; ++mi)
            sacc[mi][nf] = __builtin_amdgcn_mfma_f32_16x16x32_bf16(
                qf[mi][kk], kf, sacc[mi][nf], 0, 0, 0);
        }
      }
      __builtin_amdgcn_s_setprio(0);

      // ---- prefetch next tile (K direct to LDS, V to regs) ----
      uint4 van, vbn;
      const bool has_next = (ti + 1 < nt);
      if (has_next) {
        stage_k(lK[cur ^ 1], Kg, brow + t0 + 64, tid, wave);
        load_v(Vg, brow + t0 + 64, lane, wave, van, vbn);
      }

      // ---- mask + scale + local max ----
      const bool full = (t0 + 64 <= q0);
      float p[2][4][4];
      float mtl[2][4];
      bool okl = true;
#pragma unroll
      for (int mi = 0; mi < 2; ++mi) {
        float mt0 = -1e30f, mt1 = -1e30f, mt2 = -1e30f, mt3 = -1e30f;
#pragma unroll
        for (int nf = 0; nf < 4; ++nf) {
          const int tg = t0 + nf * 16 + lo;
#pragma unroll
          for (int r = 0; r < 4; ++r) {
            float s = sacc[mi][nf][r] * 0.125f;   // 1/sqrt(64)
            if (!full) {
              const int qg = q0w + mi * 16 + hi * 4 + r;
              if (tg > qg) s = -1e30f;
            }
            p[mi][nf][r] = s;
            if (r == 0) mt0 = fmaxf(mt0, s);
            if (r == 1) mt1 = fmaxf(mt1, s);
            if (r == 2) mt2 = fmaxf(mt2, s);
            if (r == 3) mt3 = fmaxf(mt3, s);
          }
        }
        mtl[mi][0] = mt0; mtl[mi][1] = mt1; mtl[mi][2] = mt2; mtl[mi][3] = mt3;
#pragma unroll
        for (int r = 0; r < 4; ++r) okl = okl && (mtl[mi][r] <= m_run[mi][r] + 8.f);
      }

      // ---- defer-max: full rescale only when a row max grew (T13) ----
      if (!__all((int)okl)) {
#pragma unroll
        for (int mi = 0; mi < 2; ++mi) {
#pragma unroll
          for (int r = 0; r < 4; ++r) {
            float v = mtl[mi][r];
            v = fmaxf(v, __shfl_xor(v, 1));
            v = fmaxf(v, __shfl_xor(v, 2));
            v = fmaxf(v, __shfl_xor(v, 4));
            v = fmaxf(v, __shfl_xor(v, 8));
            const float mn = fmaxf(m_run[mi][r], v);
            const float alpha = __expf(m_run[mi][r] - mn);
            m_run[mi][r] = mn;
            l_lane[mi][r] *= alpha;
#pragma unroll
            for (int nf = 0; nf < 4; ++nf) oacc[mi][nf][r] *= alpha;
          }
        }
      }

      // ---- exp + P write (trunc bf16) + lane-partial l ----
#pragma unroll
      for (int mi = 0; mi < 2; ++mi) {
#pragma unroll
        for (int r = 0; r < 4; ++r) {
          float rs = 0.f;
#pragma unroll
          for (int nf = 0; nf < 4; ++nf) {
            const float e = __expf(p[mi][nf][r] - m_run[mi][r]);
            rs += e;
            lP[wave][(mi * 16 + hi * 4 + r) * 72 + nf * 16 + lo] = f2bf_trunc(e);
          }
          l_lane[mi][r] += rs;
        }
      }

      // ---- V for next tile into other buffer (no barrier needed) ----
      if (has_next) write_v(lVt[cur ^ 1], lane, wave, van, vbn);

      // ---- O += P V ----
      __builtin_amdgcn_s_setprio(1);
#pragma unroll
      for (int kk = 0; kk < 2; ++kk) {
        bf16x8 pf[2];
#pragma unroll
        for (int mi = 0; mi < 2; ++mi)
          pf[mi] = *reinterpret_cast<const bf16x8*>(
              &lP[wave][(mi * 16 + lo) * 72 + kk * 32 + hi * 8]);
#pragma unroll
        for (int nf = 0; nf < 4; ++nf) {
          bf16x8 vf = *reinterpret_cast<const bf16x8*>(
              &lVc[(nf * 16 + lo) * 72 + kk * 32 + hi * 8]);
#pragma unroll
          for (int mi = 0; mi < 2; ++mi)
            oacc[mi][nf] = __builtin_amdgcn_mfma_f32_16x16x32_bf16(
                pf[mi], vf, oacc[mi][nf], 0, 0, 0);
        }
      }
      __builtin_amdgcn_s_setprio(0);
      __syncthreads();   // everyone done reading cur before it becomes the stage target
    }

    // ---- epilogue: reduce lane-partial l across the 16-lane group, store ----
#pragma unroll
    for (int mi = 0; mi < 2; ++mi) {
      float inv[4];
#pragma unroll
      for (int r = 0; r < 4; ++r) {
        float ls = l_lane[mi][r];
        ls += __shfl_xor(ls, 1);
        ls += __shfl_xor(ls, 2);
        ls += __shfl_xor(ls, 4);
        ls += __shfl_xor(ls, 8);
        inv[r] = 1.f / ls;
      }
#pragma unroll
      for (int nf = 0; nf < 4; ++nf)
#pragma unroll
        for (int r = 0; r < 4; ++r)
          Og[(size_t)(brow + q0w + mi * 16 + hi * 4 + r) * D_MODEL +
             h * HD + nf * 16 + lo] = f2bf(oacc[mi][nf][r] * inv[r]);
    }
  }
}

// ---------------- launcher ----------------
extern "C" void kernel_launch(void* const* d_in, const int* in_sizes, int n_in,
                              void* d_out, int out_size, void* d_ws, size_t ws_size,
                              hipStream_t stream) {
  (void)in_sizes; (void)n_in; (void)out_size; (void)ws_size;
  const float* x  = (const float*)d_in[0];
  const float* wq = (const float*)d_in[1];
  const float* wk = (const float*)d_in[2];
  const float* wv = (const float*)d_in[3];
  const float* wo = (const float*)d_in[4];
  float* out = (float*)d_out;
  char* ws = (char*)d_ws;

  double* partials = (double*)ws;            // 640 * 8 B
  float* tabs = (float*)(ws + 6144);         // 40 floats
  size_t off = 8192;
  u16* xb    = (u16*)(ws + off); off += (size_t)MROWS * D_MODEL * 2;
  u16* wqkvs = (u16*)(ws + off); off += (size_t)NQKV * D_MODEL * 2;
  u16* wos   = (u16*)(ws + off); off += (size_t)D_MODEL * D_MODEL * 2;
  u16* qkvb  = (u16*)(ws + off); off += (size_t)MROWS * NQKV * 2;
  u16* ao    = (u16*)(ws + off); off += (size_t)MROWS * D_MODEL * 2;

  // 1. weight prep (fused): signs into concat buffers + |w| partial sums
  prep_weights<<<640, 256, 0, stream>>>(wq, wk, wv, wo, wqkvs, wos, partials);
  finalize_scales<<<1, 64, 0, stream>>>(partials, tabs);

  // 2. x -> bf16
  cvt_f32_bf16<<<MROWS * D_MODEL / 4 / 256, 256, 0, stream>>>(x, xb, MROWS * D_MODEL / 4);

  // 3. fused QKV projection (N = 3072)
  gemm_bt<1><<<dim3(NQKV / 128, MROWS / 128), 256, 0, stream>>>(
      xb, wqkvs, qkvb, tabs, MROWS, NQKV, D_MODEL);

  // 4. GQA causal flash attention (balanced pairing)
  flash_attn<<<dim3(8, 64), 256, 0, stream>>>(qkvb, ao);

  // 5. output projection (f32 out)
  gemm_bt<0><<<dim3(D_MODEL / 128, MROWS / 128), 256, 0, stream>>>(
      ao, wos, out, tabs + 24, MROWS, D_MODEL, D_MODEL);
}